// Round 8
// baseline (62.667 us; speedup 1.0000x reference)
//
#include <hip/hip_runtime.h>
#include <hip/hip_bf16.h>

// RotatedEmbedding: out[m,:] = W[ids[m],:] @ R  (M=16384, K=N=1024)
// convert_R: R -> RT bf16 (transposed).  Fused gather-GEMM: 256x256 tile,
// BK=32, 8 waves. A = W rows gathered DIRECTLY via global_load_lds with
// per-lane source rows (m104: global src is per-lane) staged as raw f32,
// converted to bf16 on fragment read (packed cvt_pk, m240). B = RT bf16 via
// global_load_lds. Both sources pre-XOR-swizzled (rule #21). 3-buffer ring,
// counted vmcnt (T4, r7-proven ledger), setprio (T5), XCD swizzle (T1),
// no sched pinning (m141).

typedef __attribute__((ext_vector_type(4))) float f32x4;
typedef __attribute__((ext_vector_type(4))) int i32x4;
typedef __attribute__((ext_vector_type(8))) short s16x8;

#define DIM 1024
#define NT 32  // K-tiles (BK=32)

__device__ __forceinline__ short f2bf(float f) {
  unsigned u = __float_as_uint(f);
  unsigned r = (u + 0x7FFFu + ((u >> 16) & 1u)) >> 16;  // RNE
  return (short)r;
}

__device__ __forceinline__ int cvt2(float a, float b) {  // packed f32x2 -> bf16x2
  __hip_bfloat162 h = __float22bfloat162_rn(float2{a, b});
  return *reinterpret_cast<int*>(&h);
}

__device__ __forceinline__ void gload_lds16(const void* g, void* l) {
  __builtin_amdgcn_global_load_lds((const __attribute__((address_space(1))) void*)g,
                                   (__attribute__((address_space(3))) void*)l, 16, 0, 0);
}

// R [K][N] f32 -> RT [N][K] bf16
__global__ __launch_bounds__(256) void convert_R_kernel(const float* __restrict__ R,
                                                        short* __restrict__ RT) {
  __shared__ float tile[32][33];
  const int bx = blockIdx.x, by = blockIdx.y;
  const int tx = threadIdx.x, ty = threadIdx.y;
#pragma unroll
  for (int i = 0; i < 4; ++i)
    tile[ty + i * 8][tx] = R[(size_t)(by * 32 + ty + i * 8) * DIM + bx * 32 + tx];
  __syncthreads();
#pragma unroll
  for (int i = 0; i < 4; ++i)
    RT[(size_t)(bx * 32 + ty + i * 8) * DIM + by * 32 + tx] = f2bf(tile[tx][ty + i * 8]);
}

// Fused gather-GEMM. Grid 256 x 512. Dynamic LDS 148480 B:
// A bufs 3 x 32768 @0 (f32, 256 rows x 128 B, slot s holds chunk s^(row&7));
// B bufs 3 x 16384 @98304 (bf16, 256 rows x 64 B, slot s holds chunk s^(row&3));
// sIds @147456.
__global__ __launch_bounds__(512, 2) void rot_embed_fused(const float* __restrict__ W,
                                                          const short* __restrict__ RT,
                                                          const int* __restrict__ ids,
                                                          float* __restrict__ out) {
  extern __shared__ char smem[];

  const int t = threadIdx.x;
  const int b = blockIdx.x;
  // T1: XCD-bijective (256 blocks): XCD x -> m-panels [x*8,(x+1)*8); the 4
  // n-siblings of each m-panel share the XCD -> gathered W rows dedup in L2.
  const int swz = (b & 7) * 32 + (b >> 3);
  const int m0 = (swz >> 2) * 256;
  const int n0 = (swz & 3) * 256;

  int* sIds = (int*)(smem + 147456);
  if (t < 256) sIds[t] = ids[m0 + t];
  __syncthreads();

  const int lane = t & 63;
  const int w = t >> 6;
  const int wm = w >> 2, wn = w & 3;
  const int fr = lane & 15, fq = lane >> 4;

  char* const ldsA = smem;
  char* const ldsB = smem + 98304;
  const int ldsOff = w * 1024;

  // A staging: instr j covers rows j*64 + w*8 + (lane>>3); LDS slot lane&7
  // holds logical f32 chunk (lane&7)^(lane>>3)  [row&7 == lane>>3].
  const int cA = ((lane & 7) ^ (lane >> 3)) * 4;  // f32 col in [0,32)
  const float* gA0 = W + (size_t)sIds[0 * 64 + w * 8 + (lane >> 3)] * DIM + cA;
  const float* gA1 = W + (size_t)sIds[1 * 64 + w * 8 + (lane >> 3)] * DIM + cA;
  const float* gA2 = W + (size_t)sIds[2 * 64 + w * 8 + (lane >> 3)] * DIM + cA;
  const float* gA3 = W + (size_t)sIds[3 * 64 + w * 8 + (lane >> 3)] * DIM + cA;

  // B staging: instr j covers rows j*128 + w*16 + (lane>>2); slot lane&3 holds
  // chunk (lane&3)^((lane>>2)&3)  [row&3 == (lane>>2)&3].
  const int cB = ((lane & 3) ^ ((lane >> 2) & 3)) * 8;  // bf16 col in [0,32)
  const short* gB0 = RT + (size_t)(n0 + 0 * 128 + w * 16 + (lane >> 2)) * DIM + cB;
  const short* gB1 = RT + (size_t)(n0 + 1 * 128 + w * 16 + (lane >> 2)) * DIM + cB;

#define STAGE(buf, kt)                                                   \
  {                                                                      \
    const int ko = (kt) * 32;                                            \
    gload_lds16(gA0 + ko, ldsA + (buf) * 32768 + 0 * 8192 + ldsOff);     \
    gload_lds16(gA1 + ko, ldsA + (buf) * 32768 + 1 * 8192 + ldsOff);     \
    gload_lds16(gA2 + ko, ldsA + (buf) * 32768 + 2 * 8192 + ldsOff);     \
    gload_lds16(gA3 + ko, ldsA + (buf) * 32768 + 3 * 8192 + ldsOff);     \
    gload_lds16(gB0 + ko, ldsB + (buf) * 16384 + 0 * 8192 + ldsOff);     \
    gload_lds16(gB1 + ko, ldsB + (buf) * 16384 + 1 * 8192 + ldsOff);     \
  }

  f32x4 acc[8][4];
#pragma unroll
  for (int i = 0; i < 8; ++i)
#pragma unroll
    for (int j = 0; j < 4; ++j) acc[i][j] = (f32x4)0.0f;

  // loop-invariant swizzled read offsets
  const int xA = fr & 7;
  const int s0 = ((2 * fq) ^ xA) << 4;        // f32 chunk 2fq
  const int s1 = ((2 * fq + 1) ^ xA) << 4;    // f32 chunk 2fq+1
  const int sB = (fq ^ (fr & 3)) << 4;        // bf16 chunk fq

  // ---- prologue: 2 tiles in flight (12 vmem instrs) ----
  STAGE(0, 0);
  STAGE(1, 1);

  int b0 = 0, b1 = 1, b2 = 2;
  for (int kt = 0; kt < NT; ++kt) {
    if (kt < NT - 1)
      asm volatile("s_waitcnt vmcnt(6)" ::: "memory");  // tile kt fully landed
    else
      asm volatile("s_waitcnt vmcnt(0)" ::: "memory");
    asm volatile("s_waitcnt lgkmcnt(0)" ::: "memory");  // my prev-iter reads done
    __builtin_amdgcn_s_barrier();  // all waves: tile kt visible, old reads done

    if (kt + 2 < NT) STAGE(b2, kt + 2);  // overwrites buf read 2 iters ago

    {
      const char* A = ldsA + b0 * 32768;
      const char* B = ldsB + b0 * 16384;
      s16x8 af[8], bfv[4];
#pragma unroll
      for (int mi = 0; mi < 8; ++mi) {
        const int rbase = (wm * 128 + mi * 16 + fr) * 128;
        const f32x4 lo = *(const f32x4*)(A + rbase + s0);
        const f32x4 hi = *(const f32x4*)(A + rbase + s1);
        i32x4 v;
        v[0] = cvt2(lo[0], lo[1]);
        v[1] = cvt2(lo[2], lo[3]);
        v[2] = cvt2(hi[0], hi[1]);
        v[3] = cvt2(hi[2], hi[3]);
        af[mi] = *(s16x8*)&v;
      }
#pragma unroll
      for (int nj = 0; nj < 4; ++nj) {
        const int rb = wn * 64 + nj * 16 + fr;
        bfv[nj] = *(const s16x8*)(B + rb * 64 + sB);
      }
      __builtin_amdgcn_s_setprio(1);
#pragma unroll
      for (int mi = 0; mi < 8; ++mi)
#pragma unroll
        for (int nj = 0; nj < 4; ++nj)
          acc[mi][nj] = __builtin_amdgcn_mfma_f32_16x16x32_bf16(af[mi], bfv[nj], acc[mi][nj], 0, 0, 0);
      __builtin_amdgcn_s_setprio(0);
    }

    const int tmp = b0; b0 = b1; b1 = b2; b2 = tmp;
  }

  // ---- epilogue: D col=lane&15, row=(lane>>4)*4+reg (m89-verified) ----
#pragma unroll
  for (int mi = 0; mi < 8; ++mi)
#pragma unroll
    for (int nj = 0; nj < 4; ++nj) {
      float* op = out + (size_t)(m0 + wm * 128 + mi * 16 + fq * 4) * DIM +
                  (n0 + wn * 64 + nj * 16 + fr);
#pragma unroll
      for (int r = 0; r < 4; ++r) op[(size_t)r * DIM] = acc[mi][nj][r];
    }
#undef STAGE
}

extern "C" void kernel_launch(void* const* d_in, const int* in_sizes, int n_in,
                              void* d_out, int out_size, void* d_ws, size_t ws_size,
                              hipStream_t stream) {
  const int* ids = (const int*)d_in[0];    // [4,4096] int32
  const float* W = (const float*)d_in[1];  // [50257,1024] f32
  const float* R = (const float*)d_in[2];  // [1024,1024] f32
  float* out = (float*)d_out;              // [4,4096,1024] f32
  short* RT = (short*)d_ws;                // 2 MB bf16 R^T

  convert_R_kernel<<<dim3(32, 32), dim3(32, 8), 0, stream>>>(R, RT);
  rot_embed_fused<<<dim3(256), dim3(512), 148480, stream>>>(W, RT, ids, out);
}